// Round 8
// baseline (1379.716 us; speedup 1.0000x reference)
//
#include <hip/hip_runtime.h>

// GCN layer: out = A_coo @ (X @ W) + b
// N=100000 nodes, E=3200000 edges, D_IN=D_OUT=256.
//
// R11 = R10 with ONE change: accumulator as 48 NAMED f32x4 registers.
// R10 post-mortem: bucket-sweep locality WORKED (FETCH 764->355MB) but
// VGPR_Count=128 + WRITE_SIZE 346MB showed the switch over acc[49] was
// collapsed back into dynamic indexing -> scratch spill (rule #20) ->
// 578us of scratch round-trips. Named SSA values cannot be re-arrayed;
// switch on wave-uniform dloc compiles to a scalar jump table.
// G=48, NGRP=2084 waves (521 blocks x 4, ~all resident at 2 waves/SIMD),
// acc = 192 VGPR + ~35 overhead <= 256 cap from launch_bounds(256,2).

typedef __bf16 bf16;
typedef bf16 bf16x4 __attribute__((ext_vector_type(4)));
typedef bf16 bf16x8 __attribute__((ext_vector_type(8)));
typedef float f32x4 __attribute__((ext_vector_type(4)));
typedef int i32x2 __attribute__((ext_vector_type(2)));

#define D_DIM 256
#define NB 32          // src buckets (1.6MB of S each)
#define G 48           // dst nodes per wavegroup
#define NGRP 2084      // wavegroups = ceil(100000/48), padded to 521*4

__device__ __forceinline__ int bucket_of(unsigned s, unsigned magic) {
    unsigned b = (unsigned)(((unsigned long long)s * magic) >> 32);
    return b > (NB - 1) ? (NB - 1) : (int)b;
}
__device__ __forceinline__ int wgroup_of(unsigned d, unsigned mG) {
    return (int)(((unsigned long long)d * mG) >> 32);   // exact floor(d/G) for d<2^20
}

// ---- 1) pack W[256][256] fp32 -> bf16 MFMA B-fragment layout ----
__global__ void pack_w(const float* __restrict__ W, bf16* __restrict__ Wf) {
    int lane = threadIdx.x;           // 64
    int blk  = blockIdx.x;            // 128 = 8 kt * 16 nt
    int kt = blk >> 4, nt = blk & 15;
    int t = lane & 15, q = lane >> 4;
    int krow = kt * 32 + q * 8;
    int col  = nt * 16 + t;
    bf16x8 v;
#pragma unroll
    for (int j = 0; j < 8; ++j)
        v[j] = (bf16)W[(size_t)(krow + j) * D_DIM + col];
    ((bf16x8*)Wf)[(size_t)blk * 64 + lane] = v;
}

// ---- 2) GEMM: support = X @ W (bf16 out). One wave = 16 rows x 256 cols ----
__global__ void gemm_xw(const float* __restrict__ X, const bf16* __restrict__ Wf,
                        bf16* __restrict__ S, int N) {
    int wid  = blockIdx.x * 4 + (threadIdx.x >> 6);
    int base = wid * 16;
    if (base >= N) return;
    int lane = threadIdx.x & 63;
    int t = lane & 15, q = lane >> 4;

    const float* xrow = X + (size_t)(base + t) * D_DIM + q * 8;
    const bf16x8* wf = (const bf16x8*)Wf;

    f32x4 acc[16];
#pragma unroll
    for (int i = 0; i < 16; ++i) acc[i] = (f32x4){0.f, 0.f, 0.f, 0.f};

#pragma unroll
    for (int kt = 0; kt < 8; ++kt) {
        f32x4 x0 = *(const f32x4*)(xrow + kt * 32);
        f32x4 x1 = *(const f32x4*)(xrow + kt * 32 + 4);
        bf16x8 a;
        a[0] = (bf16)x0[0]; a[1] = (bf16)x0[1]; a[2] = (bf16)x0[2]; a[3] = (bf16)x0[3];
        a[4] = (bf16)x1[0]; a[5] = (bf16)x1[1]; a[6] = (bf16)x1[2]; a[7] = (bf16)x1[3];
#pragma unroll
        for (int nt = 0; nt < 16; ++nt) {
            bf16x8 bfr = wf[(size_t)(kt * 16 + nt) * 64 + lane];
            acc[nt] = __builtin_amdgcn_mfma_f32_16x16x32_bf16(a, bfr, acc[nt], 0, 0, 0);
        }
    }

#pragma unroll
    for (int nt = 0; nt < 16; ++nt) {
#pragma unroll
        for (int r = 0; r < 4; ++r) {
            S[(size_t)(base + q * 4 + r) * D_DIM + nt * 16 + t] = (bf16)acc[nt][r];
        }
    }
}

// ---- 3a) histogram + rank over NB*NGRP (bucket,group) keys. 8/thread ----
__global__ void rank4(const int* __restrict__ esrc, const int* __restrict__ edst,
                      int* __restrict__ cnt, int* __restrict__ erank, int E,
                      unsigned bmagic, unsigned mG) {
    int gid  = blockIdx.x * blockDim.x + threadIdx.x;
    int base = gid * 8;
    if (base + 8 <= E) {
        int4 s0 = *(const int4*)(esrc + base);
        int4 s1 = *(const int4*)(esrc + base + 4);
        int4 d0 = *(const int4*)(edst + base);
        int4 d1 = *(const int4*)(edst + base + 4);
        int4 r0, r1;
        r0.x = atomicAdd(&cnt[bucket_of(s0.x, bmagic) * NGRP + wgroup_of(d0.x, mG)], 1);
        r0.y = atomicAdd(&cnt[bucket_of(s0.y, bmagic) * NGRP + wgroup_of(d0.y, mG)], 1);
        r0.z = atomicAdd(&cnt[bucket_of(s0.z, bmagic) * NGRP + wgroup_of(d0.z, mG)], 1);
        r0.w = atomicAdd(&cnt[bucket_of(s0.w, bmagic) * NGRP + wgroup_of(d0.w, mG)], 1);
        r1.x = atomicAdd(&cnt[bucket_of(s1.x, bmagic) * NGRP + wgroup_of(d1.x, mG)], 1);
        r1.y = atomicAdd(&cnt[bucket_of(s1.y, bmagic) * NGRP + wgroup_of(d1.y, mG)], 1);
        r1.z = atomicAdd(&cnt[bucket_of(s1.z, bmagic) * NGRP + wgroup_of(d1.z, mG)], 1);
        r1.w = atomicAdd(&cnt[bucket_of(s1.w, bmagic) * NGRP + wgroup_of(d1.w, mG)], 1);
        *(int4*)(erank + base)     = r0;
        *(int4*)(erank + base + 4) = r1;
    } else {
        for (int e = base; e < E; ++e)
            erank[e] = atomicAdd(
                &cnt[bucket_of(esrc[e], bmagic) * NGRP + wgroup_of(edst[e], mG)], 1);
    }
}

// ---- 3b) per-block exclusive scan (1024 elems/block) ----
__global__ void scan_block(const int* __restrict__ counts, int n,
                           int* __restrict__ local_ex, int* __restrict__ bsums) {
    __shared__ int lds[1024];
    int tid = threadIdx.x;
    int g = blockIdx.x * 1024 + tid;
    int v = (g < n) ? counts[g] : 0;
    lds[tid] = v;
    __syncthreads();
    for (int d = 1; d < 1024; d <<= 1) {
        int add = (tid >= d) ? lds[tid - d] : 0;
        __syncthreads();
        lds[tid] += add;
        __syncthreads();
    }
    if (g < n) local_ex[g] = lds[tid] - v;
    if (tid == 1023) bsums[blockIdx.x] = lds[tid];
}

// ---- 3c) scan of block sums (single block, nb <= 128) ----
__global__ void scan_sums(const int* __restrict__ bsums, int nb, int* __restrict__ bex) {
    __shared__ int lds[128];
    int tid = threadIdx.x;
    int v = (tid < nb) ? bsums[tid] : 0;
    lds[tid] = v;
    __syncthreads();
    for (int d = 1; d < 128; d <<= 1) {
        int add = (tid >= d) ? lds[tid - d] : 0;
        __syncthreads();
        lds[tid] += add;
        __syncthreads();
    }
    if (tid < nb) bex[tid] = lds[tid] - v;
}

// ---- 3d) add block base; also writes sentinel off[n] = E ----
__global__ void add_base(int* __restrict__ off, const int* __restrict__ bex,
                         int n, int E) {
    int g = blockIdx.x * 1024 + threadIdx.x;
    if (g < n) off[g] += bex[blockIdx.x];
    if (g == 0) off[n] = E;
}

// ---- 3e) scatter (ATOMIC-FREE): pos = off[key] + rank; payload packs dloc ----
__global__ void scatter4(const int* __restrict__ esrc, const int* __restrict__ edst,
                         const float* __restrict__ evals, const int* __restrict__ erank,
                         const int* __restrict__ off, i32x2* __restrict__ eP, int E,
                         unsigned bmagic, unsigned mG) {
    int gid  = blockIdx.x * blockDim.x + threadIdx.x;
    int base = gid * 8;
    if (base + 8 <= E) {
        int4 s0 = *(const int4*)(esrc + base);
        int4 s1 = *(const int4*)(esrc + base + 4);
        int4 d0 = *(const int4*)(edst + base);
        int4 d1 = *(const int4*)(edst + base + 4);
        int4 r0 = *(const int4*)(erank + base);
        int4 r1 = *(const int4*)(erank + base + 4);
        float4 v0 = *(const float4*)(evals + base);
        float4 v1 = *(const float4*)(evals + base + 4);
        int ss[8] = {s0.x, s0.y, s0.z, s0.w, s1.x, s1.y, s1.z, s1.w};
        int dd[8] = {d0.x, d0.y, d0.z, d0.w, d1.x, d1.y, d1.z, d1.w};
        int rr[8] = {r0.x, r0.y, r0.z, r0.w, r1.x, r1.y, r1.z, r1.w};
        float vv[8] = {v0.x, v0.y, v0.z, v0.w, v1.x, v1.y, v1.z, v1.w};
#pragma unroll
        for (int j = 0; j < 8; ++j) {
            int wg = wgroup_of(dd[j], mG);
            int dl = dd[j] - wg * G;
            int key = bucket_of(ss[j], bmagic) * NGRP + wg;
            int pos = off[key] + rr[j];
            eP[pos] = (i32x2){ss[j] | (dl << 20), __float_as_int(vv[j])};
        }
    } else {
        for (int e = base; e < E; ++e) {
            int wg = wgroup_of(edst[e], mG);
            int dl = edst[e] - wg * G;
            int key = bucket_of(esrc[e], bmagic) * NGRP + wg;
            int pos = off[key] + erank[e];
            eP[pos] = (i32x2){esrc[e] | (dl << 20), __float_as_int(evals[e])};
        }
    }
}

// ---- 4) aggregate5: 2084 waves sweep 32 src-buckets together.
// Wave owns G=48 nodes; acc in 48 NAMED f32x4 registers (not an array ->
// cannot be demoted to scratch). Per-edge node index is wave-uniform ->
// scalar jump table. Lane owns cols [lane*4, lane*4+4).
#define FOR48(M) M(0) M(1) M(2) M(3) M(4) M(5) M(6) M(7) M(8) M(9) M(10) \
    M(11) M(12) M(13) M(14) M(15) M(16) M(17) M(18) M(19) M(20) M(21)    \
    M(22) M(23) M(24) M(25) M(26) M(27) M(28) M(29) M(30) M(31) M(32)    \
    M(33) M(34) M(35) M(36) M(37) M(38) M(39) M(40) M(41) M(42) M(43)    \
    M(44) M(45) M(46) M(47)

#define DECLA(i) f32x4 A##i = bias;
#define CASEA(i) case i: A##i[0]+=f0; A##i[1]+=f1; A##i[2]+=f2; A##i[3]+=f3; break;
#define STOREA(i) { int node = wbase + i;                                        \
    if (node < N) __builtin_nontemporal_store(A##i,                              \
        (f32x4*)out + (size_t)node * 64 + lane); }

#define APPLY(P, V) {                                                            \
    unsigned px = (unsigned)(P)[0];                                              \
    float wt = __int_as_float((P)[1]);                                           \
    float f0 = wt * (float)(V)[0], f1 = wt * (float)(V)[1],                      \
          f2 = wt * (float)(V)[2], f3 = wt * (float)(V)[3];                      \
    switch (px >> 20) { FOR48(CASEA) } }

__global__ void __launch_bounds__(256, 2) aggregate5(
        const bf16* __restrict__ S, const int* __restrict__ off4,
        const i32x2* __restrict__ eP, const float* __restrict__ b,
        float* __restrict__ out, int N) {
    int wid  = threadIdx.x >> 6;
    int lane = threadIdx.x & 63;
    int w    = blockIdx.x * 4 + wid;        // 0..2083 == wavegroup id

    const f32x4 bias = ((const f32x4*)b)[lane];
    FOR48(DECLA)

    for (int k = 0; k < NB; ++k) {
        int s = off4[k * NGRP + w];
        int t = off4[k * NGRP + w + 1];
        int e = s;
        for (; e + 4 <= t; e += 4) {
            i32x2 p0 = eP[e], p1 = eP[e + 1], p2 = eP[e + 2], p3 = eP[e + 3];
            bf16x4 v0 = *((const bf16x4*)(S + (size_t)(p0[0] & 0xFFFFF) * D_DIM) + lane);
            bf16x4 v1 = *((const bf16x4*)(S + (size_t)(p1[0] & 0xFFFFF) * D_DIM) + lane);
            bf16x4 v2 = *((const bf16x4*)(S + (size_t)(p2[0] & 0xFFFFF) * D_DIM) + lane);
            bf16x4 v3 = *((const bf16x4*)(S + (size_t)(p3[0] & 0xFFFFF) * D_DIM) + lane);
            APPLY(p0, v0) APPLY(p1, v1) APPLY(p2, v2) APPLY(p3, v3)
        }
        for (; e < t; ++e) {
            i32x2 p = eP[e];
            bf16x4 v = *((const bf16x4*)(S + (size_t)(p[0] & 0xFFFFF) * D_DIM) + lane);
            APPLY(p, v)
        }
    }

    int wbase = w * G;
    FOR48(STOREA)
}

extern "C" void kernel_launch(void* const* d_in, const int* in_sizes, int n_in,
                              void* d_out, int out_size, void* d_ws, size_t ws_size,
                              hipStream_t stream) {
    const float* X     = (const float*)d_in[0];
    const int*   esrc  = (const int*)d_in[1];
    const int*   edst  = (const int*)d_in[2];
    const float* evals = (const float*)d_in[3];
    const float* W     = (const float*)d_in[4];
    const float* bias  = (const float*)d_in[5];
    float* out = (float*)d_out;

    const int N = in_sizes[0] / D_DIM;   // 100000
    const int E = in_sizes[1];           // 3200000

    const int M2 = NB * NGRP;            // 66688 keys
    const unsigned bmagic = (unsigned)((((unsigned long long)NB << 32) + N - 1) / N);
    const unsigned mG = (unsigned)((((unsigned long long)1 << 32) + G - 1) / G);

    // workspace carve-up (256B aligned)
    auto alignup = [](size_t x) { return (x + 255) & ~(size_t)255; };
    char* ws = (char*)d_ws;
    size_t o = 0;
    bf16* S      = (bf16*)(ws + o); o = alignup(o + (size_t)N * D_DIM * sizeof(bf16));
    int* cnt4    = (int*)(ws + o);  o = alignup(o + (size_t)(M2 + 16) * sizeof(int));
    int* off4    = (int*)(ws + o);  o = alignup(o + (size_t)(M2 + 16) * sizeof(int));
    int* erank   = (int*)(ws + o);  o = alignup(o + (size_t)E * sizeof(int));
    int* bsums   = (int*)(ws + o);  o = alignup(o + 1024 * sizeof(int));
    int* bex     = (int*)(ws + o);  o = alignup(o + 1024 * sizeof(int));
    i32x2* eP    = (i32x2*)(ws + o); o = alignup(o + (size_t)E * sizeof(i32x2));
    bf16* Wf     = (bf16*)(ws + o); o = alignup(o + (size_t)D_DIM * D_DIM * sizeof(bf16));

    const int nwaves = (N + 15) / 16;              // gemm waves
    const int nb8    = ((E + 7) / 8 + 255) / 256;  // blocks for 8-edge kernels
    const int nbs    = (M2 + 1023) / 1024;         // 66 scan blocks (<=128)

    hipMemsetAsync(cnt4, 0, (size_t)(M2 + 16) * sizeof(int), stream);
    pack_w<<<128, 64, 0, stream>>>(W, Wf);
    gemm_xw<<<(nwaves + 3) / 4, 256, 0, stream>>>(X, Wf, S, N);
    rank4<<<nb8, 256, 0, stream>>>(esrc, edst, cnt4, erank, E, bmagic, mG);
    scan_block<<<nbs, 1024, 0, stream>>>(cnt4, M2, off4, bsums);
    scan_sums<<<1, 128, 0, stream>>>(bsums, nbs, bex);
    add_base<<<nbs, 1024, 0, stream>>>(off4, bex, M2, E);
    scatter4<<<nb8, 256, 0, stream>>>(esrc, edst, evals, erank, off4, eP, E, bmagic, mG);
    aggregate5<<<NGRP / 4, 256, 0, stream>>>(S, off4, eP, bias, out, N);
}

// Round 9
// 807.292 us; speedup vs baseline: 1.7091x; 1.7091x over previous
//
#include <hip/hip_runtime.h>

// GCN layer: out = A_coo @ (X @ W) + b
// N=100000 nodes, E=3200000 edges, D_IN=D_OUT=256.
//
// R12 = R11 with accumulator SIZED TO THE REGISTER BUDGET: G=16.
// Evidence chain:
//  - sweep locality works: FETCH 764MB(random) -> 355MB(R10) -> 275MB(R11)
//  - R10 failed: acc[49] array -> scratch spill (WRITE 346MB)
//  - R11 failed: 48 named f32x4 = 192 regs -> AGPR overflow -> 304 regs/thread
//    -> 1 wave/SIMD (Occ 12%) -> latency-serialized 953us
// G=16: 64 acc VGPRs + ~50 overhead <= 128 cap -> 4 waves/SIMD; dst>>4 /
// dst&15 replace magic division; 16-case jump table on wave-uniform dloc.

typedef __bf16 bf16;
typedef bf16 bf16x4 __attribute__((ext_vector_type(4)));
typedef bf16 bf16x8 __attribute__((ext_vector_type(8)));
typedef float f32x4 __attribute__((ext_vector_type(4)));
typedef int i32x2 __attribute__((ext_vector_type(2)));

#define D_DIM 256
#define NB 32          // src buckets (1.6MB of S each)
#define G 16           // dst nodes per wavegroup (power of 2)
#define NGRP 6250      // wavegroups = 100000/16

__device__ __forceinline__ int bucket_of(unsigned s, unsigned magic) {
    unsigned b = (unsigned)(((unsigned long long)s * magic) >> 32);
    return b > (NB - 1) ? (NB - 1) : (int)b;
}

// ---- 1) pack W[256][256] fp32 -> bf16 MFMA B-fragment layout ----
__global__ void pack_w(const float* __restrict__ W, bf16* __restrict__ Wf) {
    int lane = threadIdx.x;           // 64
    int blk  = blockIdx.x;            // 128 = 8 kt * 16 nt
    int kt = blk >> 4, nt = blk & 15;
    int t = lane & 15, q = lane >> 4;
    int krow = kt * 32 + q * 8;
    int col  = nt * 16 + t;
    bf16x8 v;
#pragma unroll
    for (int j = 0; j < 8; ++j)
        v[j] = (bf16)W[(size_t)(krow + j) * D_DIM + col];
    ((bf16x8*)Wf)[(size_t)blk * 64 + lane] = v;
}

// ---- 2) GEMM: support = X @ W (bf16 out). One wave = 16 rows x 256 cols ----
__global__ void gemm_xw(const float* __restrict__ X, const bf16* __restrict__ Wf,
                        bf16* __restrict__ S, int N) {
    int wid  = blockIdx.x * 4 + (threadIdx.x >> 6);
    int base = wid * 16;
    if (base >= N) return;
    int lane = threadIdx.x & 63;
    int t = lane & 15, q = lane >> 4;

    const float* xrow = X + (size_t)(base + t) * D_DIM + q * 8;
    const bf16x8* wf = (const bf16x8*)Wf;

    f32x4 acc[16];
#pragma unroll
    for (int i = 0; i < 16; ++i) acc[i] = (f32x4){0.f, 0.f, 0.f, 0.f};

#pragma unroll
    for (int kt = 0; kt < 8; ++kt) {
        f32x4 x0 = *(const f32x4*)(xrow + kt * 32);
        f32x4 x1 = *(const f32x4*)(xrow + kt * 32 + 4);
        bf16x8 a;
        a[0] = (bf16)x0[0]; a[1] = (bf16)x0[1]; a[2] = (bf16)x0[2]; a[3] = (bf16)x0[3];
        a[4] = (bf16)x1[0]; a[5] = (bf16)x1[1]; a[6] = (bf16)x1[2]; a[7] = (bf16)x1[3];
#pragma unroll
        for (int nt = 0; nt < 16; ++nt) {
            bf16x8 bfr = wf[(size_t)(kt * 16 + nt) * 64 + lane];
            acc[nt] = __builtin_amdgcn_mfma_f32_16x16x32_bf16(a, bfr, acc[nt], 0, 0, 0);
        }
    }

#pragma unroll
    for (int nt = 0; nt < 16; ++nt) {
#pragma unroll
        for (int r = 0; r < 4; ++r) {
            S[(size_t)(base + q * 4 + r) * D_DIM + nt * 16 + t] = (bf16)acc[nt][r];
        }
    }
}

// ---- 3a) histogram + rank over NB*NGRP (bucket,group) keys. 8/thread ----
__global__ void rank4(const int* __restrict__ esrc, const int* __restrict__ edst,
                      int* __restrict__ cnt, int* __restrict__ erank, int E,
                      unsigned bmagic) {
    int gid  = blockIdx.x * blockDim.x + threadIdx.x;
    int base = gid * 8;
    if (base + 8 <= E) {
        int4 s0 = *(const int4*)(esrc + base);
        int4 s1 = *(const int4*)(esrc + base + 4);
        int4 d0 = *(const int4*)(edst + base);
        int4 d1 = *(const int4*)(edst + base + 4);
        int4 r0, r1;
        r0.x = atomicAdd(&cnt[bucket_of(s0.x, bmagic) * NGRP + (d0.x >> 4)], 1);
        r0.y = atomicAdd(&cnt[bucket_of(s0.y, bmagic) * NGRP + (d0.y >> 4)], 1);
        r0.z = atomicAdd(&cnt[bucket_of(s0.z, bmagic) * NGRP + (d0.z >> 4)], 1);
        r0.w = atomicAdd(&cnt[bucket_of(s0.w, bmagic) * NGRP + (d0.w >> 4)], 1);
        r1.x = atomicAdd(&cnt[bucket_of(s1.x, bmagic) * NGRP + (d1.x >> 4)], 1);
        r1.y = atomicAdd(&cnt[bucket_of(s1.y, bmagic) * NGRP + (d1.y >> 4)], 1);
        r1.z = atomicAdd(&cnt[bucket_of(s1.z, bmagic) * NGRP + (d1.z >> 4)], 1);
        r1.w = atomicAdd(&cnt[bucket_of(s1.w, bmagic) * NGRP + (d1.w >> 4)], 1);
        *(int4*)(erank + base)     = r0;
        *(int4*)(erank + base + 4) = r1;
    } else {
        for (int e = base; e < E; ++e)
            erank[e] = atomicAdd(
                &cnt[bucket_of(esrc[e], bmagic) * NGRP + (edst[e] >> 4)], 1);
    }
}

// ---- 3b) per-block exclusive scan (1024 elems/block) ----
__global__ void scan_block(const int* __restrict__ counts, int n,
                           int* __restrict__ local_ex, int* __restrict__ bsums) {
    __shared__ int lds[1024];
    int tid = threadIdx.x;
    int g = blockIdx.x * 1024 + tid;
    int v = (g < n) ? counts[g] : 0;
    lds[tid] = v;
    __syncthreads();
    for (int d = 1; d < 1024; d <<= 1) {
        int add = (tid >= d) ? lds[tid - d] : 0;
        __syncthreads();
        lds[tid] += add;
        __syncthreads();
    }
    if (g < n) local_ex[g] = lds[tid] - v;
    if (tid == 1023) bsums[blockIdx.x] = lds[tid];
}

// ---- 3c) scan of block sums (single block, nb <= 256) ----
__global__ void scan_sums(const int* __restrict__ bsums, int nb, int* __restrict__ bex) {
    __shared__ int lds[256];
    int tid = threadIdx.x;
    int v = (tid < nb) ? bsums[tid] : 0;
    lds[tid] = v;
    __syncthreads();
    for (int d = 1; d < 256; d <<= 1) {
        int add = (tid >= d) ? lds[tid - d] : 0;
        __syncthreads();
        lds[tid] += add;
        __syncthreads();
    }
    if (tid < nb) bex[tid] = lds[tid] - v;
}

// ---- 3d) add block base; also writes sentinel off[n] = E ----
__global__ void add_base(int* __restrict__ off, const int* __restrict__ bex,
                         int n, int E) {
    int g = blockIdx.x * 1024 + threadIdx.x;
    if (g < n) off[g] += bex[blockIdx.x];
    if (g == 0) off[n] = E;
}

// ---- 3e) scatter (ATOMIC-FREE): pos = off[key] + rank; payload packs dloc ----
__global__ void scatter4(const int* __restrict__ esrc, const int* __restrict__ edst,
                         const float* __restrict__ evals, const int* __restrict__ erank,
                         const int* __restrict__ off, i32x2* __restrict__ eP, int E,
                         unsigned bmagic) {
    int gid  = blockIdx.x * blockDim.x + threadIdx.x;
    int base = gid * 8;
    if (base + 8 <= E) {
        int4 s0 = *(const int4*)(esrc + base);
        int4 s1 = *(const int4*)(esrc + base + 4);
        int4 d0 = *(const int4*)(edst + base);
        int4 d1 = *(const int4*)(edst + base + 4);
        int4 r0 = *(const int4*)(erank + base);
        int4 r1 = *(const int4*)(erank + base + 4);
        float4 v0 = *(const float4*)(evals + base);
        float4 v1 = *(const float4*)(evals + base + 4);
        int ss[8] = {s0.x, s0.y, s0.z, s0.w, s1.x, s1.y, s1.z, s1.w};
        int dd[8] = {d0.x, d0.y, d0.z, d0.w, d1.x, d1.y, d1.z, d1.w};
        int rr[8] = {r0.x, r0.y, r0.z, r0.w, r1.x, r1.y, r1.z, r1.w};
        float vv[8] = {v0.x, v0.y, v0.z, v0.w, v1.x, v1.y, v1.z, v1.w};
#pragma unroll
        for (int j = 0; j < 8; ++j) {
            int wg = dd[j] >> 4;
            int dl = dd[j] & 15;
            int key = bucket_of(ss[j], bmagic) * NGRP + wg;
            int pos = off[key] + rr[j];
            eP[pos] = (i32x2){ss[j] | (dl << 20), __float_as_int(vv[j])};
        }
    } else {
        for (int e = base; e < E; ++e) {
            int wg = edst[e] >> 4;
            int dl = edst[e] & 15;
            int key = bucket_of(esrc[e], bmagic) * NGRP + wg;
            int pos = off[key] + erank[e];
            eP[pos] = (i32x2){esrc[e] | (dl << 20), __float_as_int(evals[e])};
        }
    }
}

// ---- 4) aggregate6: 6250 wavegroups sweep 32 src-buckets in order.
// Wave owns G=16 nodes; acc in 16 NAMED f32x4 (64 VGPR, fits 128 cap at
// 4 waves/SIMD). Per-edge node index is wave-uniform -> 16-case jump table.
#define FOR16(M) M(0) M(1) M(2) M(3) M(4) M(5) M(6) M(7) M(8) M(9) M(10) \
    M(11) M(12) M(13) M(14) M(15)

#define DECLA(i) f32x4 A##i = bias;
#define CASEA(i) case i: A##i[0]+=f0; A##i[1]+=f1; A##i[2]+=f2; A##i[3]+=f3; break;
#define STOREA(i) __builtin_nontemporal_store(A##i,                              \
        (f32x4*)out + (size_t)(wbase + i) * 64 + lane);

#define APPLY(P, V) {                                                            \
    unsigned px = (unsigned)(P)[0];                                              \
    float wt = __int_as_float((P)[1]);                                           \
    float f0 = wt * (float)(V)[0], f1 = wt * (float)(V)[1],                      \
          f2 = wt * (float)(V)[2], f3 = wt * (float)(V)[3];                      \
    switch (px >> 20) { FOR16(CASEA) } }

__global__ void __launch_bounds__(256, 4) aggregate6(
        const bf16* __restrict__ S, const int* __restrict__ off4,
        const i32x2* __restrict__ eP, const float* __restrict__ b,
        float* __restrict__ out, int N) {
    int wid  = threadIdx.x >> 6;
    int lane = threadIdx.x & 63;
    int w    = blockIdx.x * 4 + wid;        // wavegroup id
    if (w >= NGRP) return;

    const f32x4 bias = ((const f32x4*)b)[lane];
    FOR16(DECLA)

    for (int k = 0; k < NB; ++k) {
        int s = off4[k * NGRP + w];
        int t = off4[k * NGRP + w + 1];
        int e = s;
        for (; e + 4 <= t; e += 4) {
            i32x2 p0 = eP[e], p1 = eP[e + 1], p2 = eP[e + 2], p3 = eP[e + 3];
            bf16x4 v0 = *((const bf16x4*)(S + (size_t)(p0[0] & 0xFFFFF) * D_DIM) + lane);
            bf16x4 v1 = *((const bf16x4*)(S + (size_t)(p1[0] & 0xFFFFF) * D_DIM) + lane);
            bf16x4 v2 = *((const bf16x4*)(S + (size_t)(p2[0] & 0xFFFFF) * D_DIM) + lane);
            bf16x4 v3 = *((const bf16x4*)(S + (size_t)(p3[0] & 0xFFFFF) * D_DIM) + lane);
            APPLY(p0, v0) APPLY(p1, v1) APPLY(p2, v2) APPLY(p3, v3)
        }
        for (; e < t; ++e) {
            i32x2 p = eP[e];
            bf16x4 v = *((const bf16x4*)(S + (size_t)(p[0] & 0xFFFFF) * D_DIM) + lane);
            APPLY(p, v)
        }
    }

    int wbase = w * G;
    FOR16(STOREA)
}

extern "C" void kernel_launch(void* const* d_in, const int* in_sizes, int n_in,
                              void* d_out, int out_size, void* d_ws, size_t ws_size,
                              hipStream_t stream) {
    const float* X     = (const float*)d_in[0];
    const int*   esrc  = (const int*)d_in[1];
    const int*   edst  = (const int*)d_in[2];
    const float* evals = (const float*)d_in[3];
    const float* W     = (const float*)d_in[4];
    const float* bias  = (const float*)d_in[5];
    float* out = (float*)d_out;

    const int N = in_sizes[0] / D_DIM;   // 100000
    const int E = in_sizes[1];           // 3200000

    const int M2 = NB * NGRP;            // 200000 keys
    const unsigned bmagic = (unsigned)((((unsigned long long)NB << 32) + N - 1) / N);

    // workspace carve-up (256B aligned)
    auto alignup = [](size_t x) { return (x + 255) & ~(size_t)255; };
    char* ws = (char*)d_ws;
    size_t o = 0;
    bf16* S      = (bf16*)(ws + o); o = alignup(o + (size_t)N * D_DIM * sizeof(bf16));
    int* cnt4    = (int*)(ws + o);  o = alignup(o + (size_t)(M2 + 16) * sizeof(int));
    int* off4    = (int*)(ws + o);  o = alignup(o + (size_t)(M2 + 16) * sizeof(int));
    int* erank   = (int*)(ws + o);  o = alignup(o + (size_t)E * sizeof(int));
    int* bsums   = (int*)(ws + o);  o = alignup(o + 1024 * sizeof(int));
    int* bex     = (int*)(ws + o);  o = alignup(o + 1024 * sizeof(int));
    i32x2* eP    = (i32x2*)(ws + o); o = alignup(o + (size_t)E * sizeof(i32x2));
    bf16* Wf     = (bf16*)(ws + o); o = alignup(o + (size_t)D_DIM * D_DIM * sizeof(bf16));

    const int nwaves = (N + 15) / 16;              // gemm waves
    const int nb8    = ((E + 7) / 8 + 255) / 256;  // blocks for 8-edge kernels
    const int nbs    = (M2 + 1023) / 1024;         // 196 scan blocks (<=256)

    hipMemsetAsync(cnt4, 0, (size_t)(M2 + 16) * sizeof(int), stream);
    pack_w<<<128, 64, 0, stream>>>(W, Wf);
    gemm_xw<<<(nwaves + 3) / 4, 256, 0, stream>>>(X, Wf, S, N);
    rank4<<<nb8, 256, 0, stream>>>(esrc, edst, cnt4, erank, E, bmagic);
    scan_block<<<nbs, 1024, 0, stream>>>(cnt4, M2, off4, bsums);
    scan_sums<<<1, 256, 0, stream>>>(bsums, nbs, bex);
    add_base<<<nbs, 1024, 0, stream>>>(off4, bex, M2, E);
    scatter4<<<nb8, 256, 0, stream>>>(esrc, edst, evals, erank, off4, eP, E, bmagic);
    aggregate6<<<(NGRP + 3) / 4, 256, 0, stream>>>(S, off4, eP, bias, out, N);
}